// Round 3
// baseline (669.801 us; speedup 1.0000x reference)
//
#include <hip/hip_runtime.h>
#include <cstdint>

typedef unsigned short u16;
typedef unsigned int u32;
typedef __attribute__((ext_vector_type(4))) float f32x4;
typedef __attribute__((ext_vector_type(8))) __bf16 bf16x8;
typedef __attribute__((ext_vector_type(8))) unsigned short u16x8;
typedef __attribute__((ext_vector_type(4))) unsigned int u32x4;

#define S_LEN 2048
#define BATCH 2
#define NQH 32
#define NKVH 8
#define HD 96
#define EMB 3072
#define QKVN 4608
#define KOFF 3072
#define VOFF 3840

__device__ __forceinline__ u16 f2b(float f) {
    u32 u = __float_as_uint(f);
    u32 r = (u + 0x7fffu + ((u >> 16) & 1u)) >> 16;
    return (u16)r;
}
__device__ __forceinline__ float b2f(u16 h) { return __uint_as_float(((u32)h) << 16); }
// single-instruction packed f32->bf16 (RNE, same as f2b) — T12 primitive
__device__ __forceinline__ u32 cvtpk(float lo, float hi) {
    u32 r;
    asm("v_cvt_pk_bf16_f32 %0, %1, %2" : "=v"(r) : "v"(lo), "v"(hi));
    return r;
}

// ---------------- fp32 -> bf16 bulk convert ----------------
__global__ __launch_bounds__(256) void conv_f2b(const float* __restrict__ in,
                                                u16* __restrict__ outp, int n8) {
    const int i = blockIdx.x * 256 + threadIdx.x;
    if (i >= n8) return;
    const f32x4* q = (const f32x4*)(in + (size_t)i * 8);
    const f32x4 a = q[0], b = q[1];
    u16x8 t;
#pragma unroll
    for (int j = 0; j < 4; ++j) {
        t[j] = f2b(a[j]);
        t[j + 4] = f2b(b[j]);
    }
    *(u16x8*)(outp + (size_t)i * 8) = t;
}

// ---------------- async global->LDS helper (m97 structure) ----------------
typedef __attribute__((address_space(1))) const uint32_t gas_u32;
typedef __attribute__((address_space(3))) uint32_t las_u32;
__device__ __forceinline__ void gld_lds16(const u16* g, u16* l) {
    __builtin_amdgcn_global_load_lds((gas_u32*)g, (las_u32*)l, 16, 0, 0);
}

// ---------------- GEMM (all-bf16): C[M,N] = A[M,K] * B[N,K]^T, row-stride ldc ---
// m97 structure: 128x128 tile, BK=32, linear LDS filled by global_load_lds dwordx4.
template <bool OUTF32>
__global__ __launch_bounds__(256) void gemm_bt(const u16* __restrict__ Ap,
                                               const u16* __restrict__ Bp,
                                               void* __restrict__ Cp,
                                               int M, int N, int K, int ldc) {
    __shared__ __align__(16) u16 As[128 * 32];
    __shared__ __align__(16) u16 Bs[128 * 32];
    const int tid = threadIdx.x;
    const int wave = tid >> 6, lane = tid & 63;
    const int bm = blockIdx.y * 128, bn = blockIdx.x * 128;
    const int wm = (wave >> 1) * 64, wn = (wave & 1) * 64;
    const int lrow = lane & 15, lk = (lane >> 4) * 8;
    const int ra = tid >> 2, ca = (tid & 3) * 8;

    // chunk c = wave*64+lane writes LDS linear c*16B; global row bm+ra, col-seg ca
    const u16* gA0 = Ap + (size_t)(bm + ra) * K + ca;
    const u16* gA1 = Ap + (size_t)(bm + ra + 64) * K + ca;
    const u16* gB0 = Bp + (size_t)(bn + ra) * K + ca;
    const u16* gB1 = Bp + (size_t)(bn + ra + 64) * K + ca;
    u16* lA0 = As + (tid & 192) * 8;  // wave-uniform LDS base
    u16* lA1 = lA0 + 2048;
    u16* lB0 = Bs + (tid & 192) * 8;
    u16* lB1 = lB0 + 2048;

    f32x4 acc[4][4] = {};
    for (int k0 = 0; k0 < K; k0 += 32) {
        __syncthreads();  // previous tile fully consumed
        gld_lds16(gA0 + k0, lA0);
        gld_lds16(gA1 + k0, lA1);
        gld_lds16(gB0 + k0, lB0);
        gld_lds16(gB1 + k0, lB1);
        __syncthreads();  // drains vmcnt(0) -> tile visible
        bf16x8 af[4], bfr[4];
#pragma unroll
        for (int mi = 0; mi < 4; ++mi)
            af[mi] = *(const bf16x8*)(As + (wm + mi * 16 + lrow) * 32 + lk);
#pragma unroll
        for (int ni = 0; ni < 4; ++ni)
            bfr[ni] = *(const bf16x8*)(Bs + (wn + ni * 16 + lrow) * 32 + lk);
#pragma unroll
        for (int mi = 0; mi < 4; ++mi)
#pragma unroll
            for (int ni = 0; ni < 4; ++ni)
                acc[mi][ni] = __builtin_amdgcn_mfma_f32_16x16x32_bf16(af[mi], bfr[ni],
                                                                      acc[mi][ni], 0, 0, 0);
    }
    const int orow = bm + wm + (lane >> 4) * 4;
    const int ocol = bn + wn + lrow;
#pragma unroll
    for (int mi = 0; mi < 4; ++mi)
#pragma unroll
        for (int ni = 0; ni < 4; ++ni)
#pragma unroll
            for (int r = 0; r < 4; ++r) {
                const size_t idx = (size_t)(orow + mi * 16 + r) * ldc + ocol + ni * 16;
                if constexpr (OUTF32)
                    ((float*)Cp)[idx] = acc[mi][ni][r];
                else
                    ((u16*)Cp)[idx] = f2b(acc[mi][ni][r]);
            }
}

// ---------------- RoPE in-place on q,k of bf16 qkv ----------------
__global__ __launch_bounds__(256) void gqa_rope(u16* __restrict__ qkv,
                                                const int* __restrict__ positions) {
    int i = blockIdx.x * 256 + threadIdx.x;
    const int pair = i % 48;
    int t = i / 48;
    const int head = t % (NQH + NKVH);
    const int bs = t / (NQH + NKVH);
    const int pos = positions[bs & (S_LEN - 1)];
    const size_t base = (size_t)bs * QKVN + (head < NQH ? head * HD : KOFF + (head - NQH) * HD);
    const float invf = __expf(-(float)(2 * pair) * (1.0f / 96.0f) * 9.210340371976184f);
    const float ang = (float)pos * invf;
    float sn, cs;
    __sincosf(ang, &sn, &cs);
    const float t1 = b2f(qkv[base + pair]);
    const float t2 = b2f(qkv[base + 48 + pair]);
    qkv[base + pair] = f2b(t1 * cs - t2 * sn);
    qkv[base + 48 + pair] = f2b(t2 * cs + t1 * sn);
}

// ---------------- Flash GQA v4: cvt_pk packing + defer-max rescale ----------------
__global__ __launch_bounds__(256) void gqa_attn3(const u16* __restrict__ qkv,
                                                 u16* __restrict__ out) {
    __shared__ __align__(16) u16 Ks[64 * 96];  // 12 KB
    __shared__ __align__(16) u16 Vt[96 * 72];  // 13.5 KB, V^T rows padded to 72

    const int tid = threadIdx.x;
    const int wave = tid >> 6, lane = tid & 63;
    const int lrow = lane & 15, lhi = lane >> 4;
    const int bx = blockIdx.x;
    const int qt32 = 63 - (bx >> 4);
    const int kvh = (bx >> 1) & 7, bb = bx & 1;
    const int qh = kvh * 4 + wave;
    const int srow0 = bb * S_LEN + qt32 * 32;    // first global q-row
    const int kb_last = (qt32 * 32 + 31) >> 6;   // KV tiles 0..kb_last
    const float cl2 = 0.10206207261596575f * 1.4426950408889634f;  // scale * log2(e)

    // Q B-frags in registers: bq[qt][kd], lane holds Q[q=qt*16+lrow][d=kd*32+lhi*8+j]
    bf16x8 bq[2][3];
#pragma unroll
    for (int qt = 0; qt < 2; ++qt)
#pragma unroll
        for (int kd = 0; kd < 3; ++kd)
            bq[qt][kd] = *(const bf16x8*)(qkv + (size_t)(srow0 + qt * 16 + lrow) * QKVN +
                                          qh * 96 + kd * 32 + lhi * 8);

    float m_s[2] = {-3e38f, -3e38f}, l_s[2] = {0.0f, 0.0f};
    f32x4 oacc[6][2] = {};  // O^T: lane d=dt*16+lhi*4+r, q=qt*16+lrow

    const int s0 = lrow + ((lane & 16) ? 32 : 0);  // shfl src for B-frag dw0/dw1
    const int s1 = s0 + 16;                        // dw2/dw3
    const bool khi = (lane & 32) != 0;

    const size_t kvrow0 = (size_t)(bb * S_LEN) * QKVN;
    for (int kb = 0; kb <= kb_last; ++kb) {
        __syncthreads();  // staging buffers free
        const size_t kbase = kvrow0 + (size_t)(kb * 64) * QKVN + KOFF + kvh * 96;
        const size_t vbase = kvrow0 + (size_t)(kb * 64) * QKVN + VOFF + kvh * 96;
        for (int u = tid; u < 768; u += 256) {
            const int oct = u % 12, row = u / 12;
            *(u16x8*)(Ks + row * 96 + oct * 8) =
                *(const u16x8*)(qkv + kbase + (size_t)row * QKVN + oct * 8);
        }
        for (int u = tid; u < 768; u += 256) {
            const int d = u % 96, so8 = u / 96;
            u16x8 v8;
#pragma unroll
            for (int j = 0; j < 8; ++j) v8[j] = qkv[vbase + (size_t)(so8 * 8 + j) * QKVN + d];
            *(u16x8*)(Vt + d * 72 + so8 * 8) = v8;
        }
        __syncthreads();

        // K A-frags: A[m=kseq][k=d]
        bf16x8 ka[4][3];
#pragma unroll
        for (int kt = 0; kt < 4; ++kt)
#pragma unroll
            for (int kd = 0; kd < 3; ++kd)
                ka[kt][kd] = *(const bf16x8*)(Ks + (kt * 16 + lrow) * 96 + kd * 32 + lhi * 8);

        const int qoff = qt32 * 32 - kb * 64;  // >=64 for kb<kb_last; 0 or 32 on diagonal
        const bool lastkb = (kb == kb_last);
        u32 bp[2][2][4];  // P^T B-frags

#pragma unroll
        for (int qt = 0; qt < 2; ++qt) {
            const int qrelmax = qoff + qt * 16 + 15;
            f32x4 sacc[4] = {};
#pragma unroll
            for (int kt = 0; kt < 4; ++kt) {
                if (lastkb && kt * 16 > qrelmax) continue;  // fully-masked tile
#pragma unroll
                for (int kd = 0; kd < 3; ++kd)
                    sacc[kt] = __builtin_amdgcn_mfma_f32_16x16x32_bf16(ka[kt][kd], bq[qt][kd],
                                                                       sacc[kt], 0, 0, 0);
            }
            float p[4][4];
            float mx = -3e38f;
            if (lastkb) {
                const int qrel = qoff + qt * 16 + lrow;
#pragma unroll
                for (int kt = 0; kt < 4; ++kt)
#pragma unroll
                    for (int r = 0; r < 4; ++r) {
                        const bool live = (kt * 16 + lhi * 4 + r) <= qrel;
                        const float s = live ? sacc[kt][r] : -3e38f;
                        p[kt][r] = s;
                        mx = fmaxf(mx, s);
                    }
            } else {
#pragma unroll
                for (int kt = 0; kt < 4; ++kt)
#pragma unroll
                    for (int r = 0; r < 4; ++r) {
                        p[kt][r] = sacc[kt][r];
                        mx = fmaxf(mx, sacc[kt][r]);
                    }
            }
            mx = fmaxf(mx, __shfl_xor(mx, 16));
            mx = fmaxf(mx, __shfl_xor(mx, 32));
            // T13 defer-max: skip rescale while max growth <= 20 raw-score units
            float mn = m_s[qt];
            if (!__all(mx - mn <= 20.0f)) {
                const float mnew = fmaxf(mn, mx);
                const float alpha = exp2f((mn - mnew) * cl2);
                m_s[qt] = mnew;
                mn = mnew;
                l_s[qt] *= alpha;
#pragma unroll
                for (int dt = 0; dt < 6; ++dt)
#pragma unroll
                    for (int r = 0; r < 4; ++r) oacc[dt][qt][r] *= alpha;
            }
            float rs = 0.0f;
#pragma unroll
            for (int kt = 0; kt < 4; ++kt)
#pragma unroll
                for (int r = 0; r < 4; ++r) {
                    const float pv = exp2f((p[kt][r] - mn) * cl2);  // masked -> exp2(-inf)=0
                    p[kt][r] = pv;
                    rs += pv;
                }
            rs += __shfl_xor(rs, 16);
            rs += __shfl_xor(rs, 32);
            l_s[qt] += rs;
            // pack (1-instr cvt_pk) + C-layout -> B-frag shuffle transpose
            u32 pk[4][2];
#pragma unroll
            for (int kt = 0; kt < 4; ++kt) {
                pk[kt][0] = cvtpk(p[kt][0], p[kt][1]);
                pk[kt][1] = cvtpk(p[kt][2], p[kt][3]);
            }
#pragma unroll
            for (int kk = 0; kk < 2; ++kk) {
                const u32 a0 = (u32)__shfl((int)pk[kk * 2][0], s0, 64);
                const u32 b0 = (u32)__shfl((int)pk[kk * 2 + 1][0], s0, 64);
                const u32 a1 = (u32)__shfl((int)pk[kk * 2][1], s0, 64);
                const u32 b1 = (u32)__shfl((int)pk[kk * 2 + 1][1], s0, 64);
                const u32 a2 = (u32)__shfl((int)pk[kk * 2][0], s1, 64);
                const u32 b2 = (u32)__shfl((int)pk[kk * 2 + 1][0], s1, 64);
                const u32 a3 = (u32)__shfl((int)pk[kk * 2][1], s1, 64);
                const u32 b3 = (u32)__shfl((int)pk[kk * 2 + 1][1], s1, 64);
                bp[qt][kk][0] = khi ? b0 : a0;
                bp[qt][kk][1] = khi ? b1 : a1;
                bp[qt][kk][2] = khi ? b2 : a2;
                bp[qt][kk][3] = khi ? b3 : a3;
            }
        }

        // O^T += V^T . P^T
#pragma unroll
        for (int dt = 0; dt < 6; ++dt) {
            bf16x8 va[2];
#pragma unroll
            for (int kk = 0; kk < 2; ++kk)
                va[kk] = *(const bf16x8*)(Vt + (dt * 16 + lrow) * 72 + kk * 32 + lhi * 8);
#pragma unroll
            for (int qt = 0; qt < 2; ++qt)
#pragma unroll
                for (int kk = 0; kk < 2; ++kk) {
                    const u32x4 bv = {bp[qt][kk][0], bp[qt][kk][1], bp[qt][kk][2], bp[qt][kk][3]};
                    oacc[dt][qt] = __builtin_amdgcn_mfma_f32_16x16x32_bf16(
                        va[kk], __builtin_bit_cast(bf16x8, bv), oacc[dt][qt], 0, 0, 0);
                }
        }
    }

    // epilogue: lane holds O^T[d=dt*16+lhi*4+r][q=qt*16+lrow]
    const size_t obase = (size_t)srow0 * EMB + qh * 96;
#pragma unroll
    for (int qt = 0; qt < 2; ++qt) {
        const float inv = 1.0f / l_s[qt];
        const size_t rbase = obase + (size_t)(qt * 16 + lrow) * EMB;
#pragma unroll
        for (int dt = 0; dt < 6; ++dt)
#pragma unroll
            for (int rp = 0; rp < 2; ++rp) {
                const u32 pair = cvtpk(oacc[dt][qt][2 * rp] * inv, oacc[dt][qt][2 * rp + 1] * inv);
                *(u32*)(out + rbase + dt * 16 + lhi * 4 + 2 * rp) = pair;
            }
    }
}

extern "C" void kernel_launch(void* const* d_in, const int* in_sizes, int n_in,
                              void* d_out, int out_size, void* d_ws, size_t ws_size,
                              hipStream_t stream) {
    const float* x = (const float*)d_in[0];
    const int* positions = (const int*)d_in[1];
    const float* W_qkv = (const float*)d_in[3];
    const float* W_o = (const float*)d_in[4];
    float* out = (float*)d_out;

    const int M = BATCH * S_LEN;                 // 4096
    const size_t QKV_E = (size_t)M * QKVN;       // 18,874,368
    const size_t ATT_E = (size_t)M * EMB;        // 12,582,912
    const size_t X_E = (size_t)M * EMB;          // 12,582,912
    const size_t WQ_E = (size_t)EMB * EMB;       // 9,437,184  (Q rows of W_qkv)
    const size_t WKV_E = (size_t)1536 * EMB;     // 4,718,592  (K+V rows)
    const size_t WO_E = (size_t)EMB * EMB;       // 9,437,184

    // Workspace plan (needs exactly (QKV_E + ATT_E)*2 = 62,914,560 B — proven to fit):
    //   ws[0 : QKV_E)              qkv (bf16)             ... later reused for wob
    //   ws[QKV_E : QKV_E+ATT_E)    scratch: wkvb -> wqb -> attn_out (serial lifetimes)
    //   d_out[0 : X_E)             xb (bf16 x; dead before GEMM2 writes out)
    u16* qkv = (u16*)d_ws;
    u16* scratch = qkv + QKV_E;
    u16* xb = (u16*)d_out;

    // 1) convert x -> bf16 (into d_out)
    conv_f2b<<<(int)(X_E / 8 / 256), 256, 0, stream>>>(x, xb, (int)(X_E / 8));

    // 2) KV part: convert W_qkv rows [3072,4608) -> scratch; GEMM into qkv cols [3072,4608)
    conv_f2b<<<(int)(WKV_E / 8 / 256), 256, 0, stream>>>(W_qkv + (size_t)EMB * EMB, scratch,
                                                         (int)(WKV_E / 8));
    gemm_bt<false><<<dim3(1536 / 128, M / 128), 256, 0, stream>>>(xb, scratch, qkv + KOFF, M,
                                                                  1536, EMB, QKVN);

    // 3) Q part: convert W_qkv rows [0,3072) -> scratch (overwrites wkvb); GEMM into qkv cols [0,3072)
    conv_f2b<<<(int)(WQ_E / 8 / 256), 256, 0, stream>>>(W_qkv, scratch, (int)(WQ_E / 8));
    gemm_bt<false><<<dim3(EMB / 128, M / 128), 256, 0, stream>>>(xb, scratch, qkv, M, EMB, EMB,
                                                                 QKVN);

    // 4) RoPE in-place on q,k
    gqa_rope<<<(BATCH * S_LEN * (NQH + NKVH) * 48) / 256, 256, 0, stream>>>(qkv, positions);

    // 5) attention -> scratch (overwrites wqb; exact 25,165,824 B fit)
    gqa_attn3<<<dim3(1024), 256, 0, stream>>>(qkv, scratch);

    // 6) convert W_o -> bf16 into ws[0:WO_E) (qkv dead after attn)
    u16* wob = (u16*)d_ws;
    conv_f2b<<<(int)(WO_E / 8 / 256), 256, 0, stream>>>(W_o, wob, (int)(WO_E / 8));

    // 7) output GEMM (fp32 out into d_out; xb region is dead)
    gemm_bt<true><<<dim3(EMB / 128, M / 128), 256, 0, stream>>>(scratch, wob, out, M, EMB, EMB,
                                                                EMB);
}

// Round 4
// 612.063 us; speedup vs baseline: 1.0943x; 1.0943x over previous
//
#include <hip/hip_runtime.h>
#include <cstdint>

typedef unsigned short u16;
typedef unsigned int u32;
typedef __attribute__((ext_vector_type(4))) float f32x4;
typedef __attribute__((ext_vector_type(8))) __bf16 bf16x8;
typedef __attribute__((ext_vector_type(8))) unsigned short u16x8;
typedef __attribute__((ext_vector_type(4))) unsigned int u32x4;

#define S_LEN 2048
#define BATCH 2
#define NQH 32
#define NKVH 8
#define HD 96
#define EMB 3072
#define QKVN 4608
#define KOFF 3072
#define VOFF 3840

__device__ __forceinline__ u16 f2b(float f) {
    u32 u = __float_as_uint(f);
    u32 r = (u + 0x7fffu + ((u >> 16) & 1u)) >> 16;
    return (u16)r;
}
__device__ __forceinline__ float b2f(u16 h) { return __uint_as_float(((u32)h) << 16); }
__device__ __forceinline__ u32 cvtpk(float lo, float hi) {
    u32 r;
    asm("v_cvt_pk_bf16_f32 %0, %1, %2" : "=v"(r) : "v"(lo), "v"(hi));
    return r;
}

// ---------------- fp32 -> bf16 bulk convert ----------------
__global__ __launch_bounds__(256) void conv_f2b(const float* __restrict__ in,
                                                u16* __restrict__ outp, int n8) {
    const int i = blockIdx.x * 256 + threadIdx.x;
    if (i >= n8) return;
    const f32x4* q = (const f32x4*)(in + (size_t)i * 8);
    const f32x4 a = q[0], b = q[1];
    u16x8 t;
#pragma unroll
    for (int j = 0; j < 4; ++j) {
        t[j] = f2b(a[j]);
        t[j + 4] = f2b(b[j]);
    }
    *(u16x8*)(outp + (size_t)i * 8) = t;
}

// ---------------- async global->LDS helper ----------------
typedef __attribute__((address_space(1))) const uint32_t gas_u32;
typedef __attribute__((address_space(3))) uint32_t las_u32;
__device__ __forceinline__ void gld_lds16(const u16* g, u16* l) {
    __builtin_amdgcn_global_load_lds((gas_u32*)g, (las_u32*)l, 16, 0, 0);
}

#define WAITV4 asm volatile("s_waitcnt vmcnt(4)" ::: "memory")
#define WAITV0 asm volatile("s_waitcnt vmcnt(0)" ::: "memory")
#define BARRIER __builtin_amdgcn_s_barrier()
#define SCHEDB __builtin_amdgcn_sched_barrier(0)

// ---------------- Pipelined GEMM: C[M,N] = A[M,K] * B[N,K]^T ----------------
// 128x128 tile, BK=64, 4 waves, double-buffered LDS (2 x 32KB), counted vmcnt(4).
// Tile t: 4 phases (k-half x n-half); tile t+1 staged one K-half unit per phase.
// LDS layout per buffer: [A|B][khalf][128 rows][32 cols], 64B rows, XOR-swizzled:
//   stored slot sigma at row r holds logical 16B slot sigma ^ (r&3) ^ ((r>>2)&3).
// gld_lds writes linearly -> inverse swizzle applied to the GLOBAL source column.
template <bool OUTF32>
__global__ __launch_bounds__(256, 2) void gemm_bt_p(const u16* __restrict__ Ap,
                                                    const u16* __restrict__ Bp,
                                                    void* __restrict__ Cp,
                                                    int M, int N, int K, int ldc) {
    __shared__ __align__(16) u16 S[2 * 16384];  // 64 KB: [buf][A/B 8192][khalf 4096]
    const int tid = threadIdx.x;
    const int wave = tid >> 6, lane = tid & 63;
    const int lrow = lane & 15, lhi = lane >> 4;
    const int bm = blockIdx.y * 128, bn = blockIdx.x * 128;
    const int wm = (wave >> 1) * 64, wn = (wave & 1) * 64;
    // read-side swizzled slot (u16 units), lane-constant: slot = lhi ^ m(row)
    const int xsl = ((lhi ^ (lrow & 3) ^ ((lrow >> 2) & 3)) << 3);
    // stage-side: thread covers rows srow (L=0) and srow+64 (L=1); source col inverse-swizzled
    const int srow = tid >> 2;
    const int scol = (((tid & 3) ^ ((tid >> 2) & 3) ^ ((tid >> 4) & 3))) * 8;
    const u16* gA0 = Ap + (size_t)(bm + srow) * K + scol;
    const u16* gA1 = Ap + (size_t)(bm + 64 + srow) * K + scol;
    const u16* gB0 = Bp + (size_t)(bn + srow) * K + scol;
    const u16* gB1 = Bp + (size_t)(bn + 64 + srow) * K + scol;
    u16* const dbase = S + (tid & 192) * 8;  // + wave*1024B (wave-uniform)

    f32x4 acc[4][4] = {};
    const int nt = K >> 6;

    // prologue: stage tile 0 into buf0, unit order Ak0, Bk0, Ak1, Bk1
    gld_lds16(gA0, dbase);
    gld_lds16(gA1, dbase + 2048);
    gld_lds16(gB0, dbase + 8192);
    gld_lds16(gB1, dbase + 8192 + 2048);
    gld_lds16(gA0 + 32, dbase + 4096);
    gld_lds16(gA1 + 32, dbase + 4096 + 2048);
    gld_lds16(gB0 + 32, dbase + 8192 + 4096);
    gld_lds16(gB1 + 32, dbase + 8192 + 4096 + 2048);

    for (int t = 0; t + 1 < nt; ++t) {
        const int cur = t & 1;
        const u16* Ab = S + cur * 16384;
        const u16* Bb = Ab + 8192;
        u16* dn = dbase + (cur ^ 1) * 16384;
        const int ko = (t + 1) << 6;

        WAITV4;  // Ak0(t), Bk0(t) landed (per wave); barrier propagates to all waves
        BARRIER;
        SCHEDB;
        // ---- P0: stage Ak0(t+1); compute h0, n-frags 0-1 ----
        gld_lds16(gA0 + ko, dn);
        gld_lds16(gA1 + ko, dn + 2048);
        bf16x8 af[4], bf0[2], bf1[2];
#pragma unroll
        for (int mi = 0; mi < 4; ++mi)
            af[mi] = *(const bf16x8*)(Ab + (wm + mi * 16 + lrow) * 32 + xsl);
#pragma unroll
        for (int ni = 0; ni < 2; ++ni)
            bf0[ni] = *(const bf16x8*)(Bb + (wn + ni * 16 + lrow) * 32 + xsl);
        __builtin_amdgcn_s_setprio(1);
#pragma unroll
        for (int mi = 0; mi < 4; ++mi)
#pragma unroll
            for (int ni = 0; ni < 2; ++ni)
                acc[mi][ni] = __builtin_amdgcn_mfma_f32_16x16x32_bf16(af[mi], bf0[ni],
                                                                      acc[mi][ni], 0, 0, 0);
        __builtin_amdgcn_s_setprio(0);
        // ---- P1: stage Bk0(t+1); compute h0, n-frags 2-3 ----
        gld_lds16(gB0 + ko, dn + 8192);
        gld_lds16(gB1 + ko, dn + 8192 + 2048);
#pragma unroll
        for (int ni = 0; ni < 2; ++ni)
            bf1[ni] = *(const bf16x8*)(Bb + (wn + (ni + 2) * 16 + lrow) * 32 + xsl);
        __builtin_amdgcn_s_setprio(1);
#pragma unroll
        for (int mi = 0; mi < 4; ++mi)
#pragma unroll
            for (int ni = 0; ni < 2; ++ni)
                acc[mi][ni + 2] = __builtin_amdgcn_mfma_f32_16x16x32_bf16(af[mi], bf1[ni],
                                                                          acc[mi][ni + 2], 0, 0, 0);
        __builtin_amdgcn_s_setprio(0);

        WAITV4;  // Ak1(t), Bk1(t) landed
        BARRIER;
        SCHEDB;
        // ---- P2: stage Ak1(t+1); compute h1, n-frags 0-1 ----
        gld_lds16(gA0 + ko + 32, dn + 4096);
        gld_lds16(gA1 + ko + 32, dn + 4096 + 2048);
#pragma unroll
        for (int mi = 0; mi < 4; ++mi)
            af[mi] = *(const bf16x8*)(Ab + 4096 + (wm + mi * 16 + lrow) * 32 + xsl);
#pragma unroll
        for (int ni = 0; ni < 2; ++ni)
            bf0[ni] = *(const bf16x8*)(Bb + 4096 + (wn + ni * 16 + lrow) * 32 + xsl);
        __builtin_amdgcn_s_setprio(1);
#pragma unroll
        for (int mi = 0; mi < 4; ++mi)
#pragma unroll
            for (int ni = 0; ni < 2; ++ni)
                acc[mi][ni] = __builtin_amdgcn_mfma_f32_16x16x32_bf16(af[mi], bf0[ni],
                                                                      acc[mi][ni], 0, 0, 0);
        __builtin_amdgcn_s_setprio(0);
        // ---- P3: stage Bk1(t+1); compute h1, n-frags 2-3 ----
        gld_lds16(gB0 + ko + 32, dn + 8192 + 4096);
        gld_lds16(gB1 + ko + 32, dn + 8192 + 4096 + 2048);
#pragma unroll
        for (int ni = 0; ni < 2; ++ni)
            bf1[ni] = *(const bf16x8*)(Bb + 4096 + (wn + (ni + 2) * 16 + lrow) * 32 + xsl);
        __builtin_amdgcn_s_setprio(1);
#pragma unroll
        for (int mi = 0; mi < 4; ++mi)
#pragma unroll
            for (int ni = 0; ni < 2; ++ni)
                acc[mi][ni + 2] = __builtin_amdgcn_mfma_f32_16x16x32_bf16(af[mi], bf1[ni],
                                                                          acc[mi][ni + 2], 0, 0, 0);
        __builtin_amdgcn_s_setprio(0);
    }

    // ---- tail tile nt-1: no staging; drain k1 with vmcnt(0) ----
    {
        const int cur = (nt - 1) & 1;
        const u16* Ab = S + cur * 16384;
        const u16* Bb = Ab + 8192;
        WAITV4;
        BARRIER;
        SCHEDB;
        bf16x8 af[4], bfr[4];
#pragma unroll
        for (int mi = 0; mi < 4; ++mi)
            af[mi] = *(const bf16x8*)(Ab + (wm + mi * 16 + lrow) * 32 + xsl);
#pragma unroll
        for (int ni = 0; ni < 4; ++ni)
            bfr[ni] = *(const bf16x8*)(Bb + (wn + ni * 16 + lrow) * 32 + xsl);
#pragma unroll
        for (int mi = 0; mi < 4; ++mi)
#pragma unroll
            for (int ni = 0; ni < 4; ++ni)
                acc[mi][ni] = __builtin_amdgcn_mfma_f32_16x16x32_bf16(af[mi], bfr[ni],
                                                                      acc[mi][ni], 0, 0, 0);
        WAITV0;
        BARRIER;
        SCHEDB;
#pragma unroll
        for (int mi = 0; mi < 4; ++mi)
            af[mi] = *(const bf16x8*)(Ab + 4096 + (wm + mi * 16 + lrow) * 32 + xsl);
#pragma unroll
        for (int ni = 0; ni < 4; ++ni)
            bfr[ni] = *(const bf16x8*)(Bb + 4096 + (wn + ni * 16 + lrow) * 32 + xsl);
#pragma unroll
        for (int mi = 0; mi < 4; ++mi)
#pragma unroll
            for (int ni = 0; ni < 4; ++ni)
                acc[mi][ni] = __builtin_amdgcn_mfma_f32_16x16x32_bf16(af[mi], bfr[ni],
                                                                      acc[mi][ni], 0, 0, 0);
    }

    const int orow = bm + wm + lhi * 4;
    const int ocol = bn + wn + lrow;
#pragma unroll
    for (int mi = 0; mi < 4; ++mi)
#pragma unroll
        for (int ni = 0; ni < 4; ++ni)
#pragma unroll
            for (int r = 0; r < 4; ++r) {
                const size_t idx = (size_t)(orow + mi * 16 + r) * ldc + ocol + ni * 16;
                if constexpr (OUTF32)
                    ((float*)Cp)[idx] = acc[mi][ni][r];
                else
                    ((u16*)Cp)[idx] = f2b(acc[mi][ni][r]);
            }
}

// ---------------- RoPE in-place on q,k of bf16 qkv ----------------
__global__ __launch_bounds__(256) void gqa_rope(u16* __restrict__ qkv,
                                                const int* __restrict__ positions) {
    int i = blockIdx.x * 256 + threadIdx.x;
    const int pair = i % 48;
    int t = i / 48;
    const int head = t % (NQH + NKVH);
    const int bs = t / (NQH + NKVH);
    const int pos = positions[bs & (S_LEN - 1)];
    const size_t base = (size_t)bs * QKVN + (head < NQH ? head * HD : KOFF + (head - NQH) * HD);
    const float invf = __expf(-(float)(2 * pair) * (1.0f / 96.0f) * 9.210340371976184f);
    const float ang = (float)pos * invf;
    float sn, cs;
    __sincosf(ang, &sn, &cs);
    const float t1 = b2f(qkv[base + pair]);
    const float t2 = b2f(qkv[base + 48 + pair]);
    qkv[base + pair] = f2b(t1 * cs - t2 * sn);
    qkv[base + 48 + pair] = f2b(t2 * cs + t1 * sn);
}

// ---------------- Flash GQA: cvt_pk packing + defer-max rescale ----------------
__global__ __launch_bounds__(256) void gqa_attn3(const u16* __restrict__ qkv,
                                                 u16* __restrict__ out) {
    __shared__ __align__(16) u16 Ks[64 * 96];
    __shared__ __align__(16) u16 Vt[96 * 72];

    const int tid = threadIdx.x;
    const int wave = tid >> 6, lane = tid & 63;
    const int lrow = lane & 15, lhi = lane >> 4;
    const int bx = blockIdx.x;
    const int qt32 = 63 - (bx >> 4);
    const int kvh = (bx >> 1) & 7, bb = bx & 1;
    const int qh = kvh * 4 + wave;
    const int srow0 = bb * S_LEN + qt32 * 32;
    const int kb_last = (qt32 * 32 + 31) >> 6;
    const float cl2 = 0.10206207261596575f * 1.4426950408889634f;

    bf16x8 bq[2][3];
#pragma unroll
    for (int qt = 0; qt < 2; ++qt)
#pragma unroll
        for (int kd = 0; kd < 3; ++kd)
            bq[qt][kd] = *(const bf16x8*)(qkv + (size_t)(srow0 + qt * 16 + lrow) * QKVN +
                                          qh * 96 + kd * 32 + lhi * 8);

    float m_s[2] = {-3e38f, -3e38f}, l_s[2] = {0.0f, 0.0f};
    f32x4 oacc[6][2] = {};

    const int s0 = lrow + ((lane & 16) ? 32 : 0);
    const int s1 = s0 + 16;
    const bool khi = (lane & 32) != 0;

    const size_t kvrow0 = (size_t)(bb * S_LEN) * QKVN;
    for (int kb = 0; kb <= kb_last; ++kb) {
        __syncthreads();
        const size_t kbase = kvrow0 + (size_t)(kb * 64) * QKVN + KOFF + kvh * 96;
        const size_t vbase = kvrow0 + (size_t)(kb * 64) * QKVN + VOFF + kvh * 96;
        for (int u = tid; u < 768; u += 256) {
            const int oct = u % 12, row = u / 12;
            *(u16x8*)(Ks + row * 96 + oct * 8) =
                *(const u16x8*)(qkv + kbase + (size_t)row * QKVN + oct * 8);
        }
        for (int u = tid; u < 768; u += 256) {
            const int d = u % 96, so8 = u / 96;
            u16x8 v8;
#pragma unroll
            for (int j = 0; j < 8; ++j) v8[j] = qkv[vbase + (size_t)(so8 * 8 + j) * QKVN + d];
            *(u16x8*)(Vt + d * 72 + so8 * 8) = v8;
        }
        __syncthreads();

        bf16x8 ka[4][3];
#pragma unroll
        for (int kt = 0; kt < 4; ++kt)
#pragma unroll
            for (int kd = 0; kd < 3; ++kd)
                ka[kt][kd] = *(const bf16x8*)(Ks + (kt * 16 + lrow) * 96 + kd * 32 + lhi * 8);

        const int qoff = qt32 * 32 - kb * 64;
        const bool lastkb = (kb == kb_last);
        u32 bp[2][2][4];

#pragma unroll
        for (int qt = 0; qt < 2; ++qt) {
            const int qrelmax = qoff + qt * 16 + 15;
            f32x4 sacc[4] = {};
#pragma unroll
            for (int kt = 0; kt < 4; ++kt) {
                if (lastkb && kt * 16 > qrelmax) continue;
#pragma unroll
                for (int kd = 0; kd < 3; ++kd)
                    sacc[kt] = __builtin_amdgcn_mfma_f32_16x16x32_bf16(ka[kt][kd], bq[qt][kd],
                                                                       sacc[kt], 0, 0, 0);
            }
            float p[4][4];
            float mx = -3e38f;
            if (lastkb) {
                const int qrel = qoff + qt * 16 + lrow;
#pragma unroll
                for (int kt = 0; kt < 4; ++kt)
#pragma unroll
                    for (int r = 0; r < 4; ++r) {
                        const bool live = (kt * 16 + lhi * 4 + r) <= qrel;
                        const float s = live ? sacc[kt][r] : -3e38f;
                        p[kt][r] = s;
                        mx = fmaxf(mx, s);
                    }
            } else {
#pragma unroll
                for (int kt = 0; kt < 4; ++kt)
#pragma unroll
                    for (int r = 0; r < 4; ++r) {
                        p[kt][r] = sacc[kt][r];
                        mx = fmaxf(mx, sacc[kt][r]);
                    }
            }
            mx = fmaxf(mx, __shfl_xor(mx, 16));
            mx = fmaxf(mx, __shfl_xor(mx, 32));
            float mn = m_s[qt];
            if (!__all(mx - mn <= 20.0f)) {
                const float mnew = fmaxf(mn, mx);
                const float alpha = exp2f((mn - mnew) * cl2);
                m_s[qt] = mnew;
                mn = mnew;
                l_s[qt] *= alpha;
#pragma unroll
                for (int dt = 0; dt < 6; ++dt)
#pragma unroll
                    for (int r = 0; r < 4; ++r) oacc[dt][qt][r] *= alpha;
            }
            float rs = 0.0f;
#pragma unroll
            for (int kt = 0; kt < 4; ++kt)
#pragma unroll
                for (int r = 0; r < 4; ++r) {
                    const float pv = exp2f((p[kt][r] - mn) * cl2);
                    p[kt][r] = pv;
                    rs += pv;
                }
            rs += __shfl_xor(rs, 16);
            rs += __shfl_xor(rs, 32);
            l_s[qt] += rs;
            u32 pk[4][2];
#pragma unroll
            for (int kt = 0; kt < 4; ++kt) {
                pk[kt][0] = cvtpk(p[kt][0], p[kt][1]);
                pk[kt][1] = cvtpk(p[kt][2], p[kt][3]);
            }
#pragma unroll
            for (int kk = 0; kk < 2; ++kk) {
                const u32 a0 = (u32)__shfl((int)pk[kk * 2][0], s0, 64);
                const u32 b0 = (u32)__shfl((int)pk[kk * 2 + 1][0], s0, 64);
                const u32 a1 = (u32)__shfl((int)pk[kk * 2][1], s0, 64);
                const u32 b1 = (u32)__shfl((int)pk[kk * 2 + 1][1], s0, 64);
                const u32 a2 = (u32)__shfl((int)pk[kk * 2][0], s1, 64);
                const u32 b2 = (u32)__shfl((int)pk[kk * 2 + 1][0], s1, 64);
                const u32 a3 = (u32)__shfl((int)pk[kk * 2][1], s1, 64);
                const u32 b3 = (u32)__shfl((int)pk[kk * 2 + 1][1], s1, 64);
                bp[qt][kk][0] = khi ? b0 : a0;
                bp[qt][kk][1] = khi ? b1 : a1;
                bp[qt][kk][2] = khi ? b2 : a2;
                bp[qt][kk][3] = khi ? b3 : a3;
            }
        }

#pragma unroll
        for (int dt = 0; dt < 6; ++dt) {
            bf16x8 va[2];
#pragma unroll
            for (int kk = 0; kk < 2; ++kk)
                va[kk] = *(const bf16x8*)(Vt + (dt * 16 + lrow) * 72 + kk * 32 + lhi * 8);
#pragma unroll
            for (int qt = 0; qt < 2; ++qt)
#pragma unroll
                for (int kk = 0; kk < 2; ++kk) {
                    const u32x4 bv = {bp[qt][kk][0], bp[qt][kk][1], bp[qt][kk][2], bp[qt][kk][3]};
                    oacc[dt][qt] = __builtin_amdgcn_mfma_f32_16x16x32_bf16(
                        va[kk], __builtin_bit_cast(bf16x8, bv), oacc[dt][qt], 0, 0, 0);
                }
        }
    }

    const size_t obase = (size_t)srow0 * EMB + qh * 96;
#pragma unroll
    for (int qt = 0; qt < 2; ++qt) {
        const float inv = 1.0f / l_s[qt];
        const size_t rbase = obase + (size_t)(qt * 16 + lrow) * EMB;
#pragma unroll
        for (int dt = 0; dt < 6; ++dt)
#pragma unroll
            for (int rp = 0; rp < 2; ++rp) {
                const u32 pair = cvtpk(oacc[dt][qt][2 * rp] * inv, oacc[dt][qt][2 * rp + 1] * inv);
                *(u32*)(out + rbase + dt * 16 + lhi * 4 + 2 * rp) = pair;
            }
    }
}

extern "C" void kernel_launch(void* const* d_in, const int* in_sizes, int n_in,
                              void* d_out, int out_size, void* d_ws, size_t ws_size,
                              hipStream_t stream) {
    const float* x = (const float*)d_in[0];
    const int* positions = (const int*)d_in[1];
    const float* W_qkv = (const float*)d_in[3];
    const float* W_o = (const float*)d_in[4];
    float* out = (float*)d_out;

    const int M = BATCH * S_LEN;               // 4096
    const size_t QKV_E = (size_t)M * QKVN;     // 18,874,368
    const size_t ATT_E = (size_t)M * EMB;      // 12,582,912
    const size_t X_E = (size_t)M * EMB;
    const size_t WQKV_E = (size_t)QKVN * EMB;  // 14,155,776 (28.3 MB bf16)
    const size_t WO_E = (size_t)EMB * EMB;     // 9,437,184

    // ws (62.9 MB, proven): qkv [0,QKV_E) ; scratch [QKV_E,+ATT_E) = xb -> attn_out
    // d_out (50.3 MB): wqkvb (28.3 MB, dead after GEMM1; overwritten by final out)
    u16* qkv = (u16*)d_ws;
    u16* scratch = qkv + QKV_E;
    u16* xb = scratch;
    u16* wqkvb = (u16*)d_out;
    u16* wob = (u16*)d_ws;  // overwrites qkv head after attn

    conv_f2b<<<(int)(X_E / 8 / 256), 256, 0, stream>>>(x, xb, (int)(X_E / 8));
    conv_f2b<<<(int)(WQKV_E / 8 / 256), 256, 0, stream>>>(W_qkv, wqkvb, (int)(WQKV_E / 8));
    gemm_bt_p<false>
        <<<dim3(QKVN / 128, M / 128), 256, 0, stream>>>(xb, wqkvb, qkv, M, QKVN, EMB, QKVN);
    gqa_rope<<<(BATCH * S_LEN * (NQH + NKVH) * 48) / 256, 256, 0, stream>>>(qkv, positions);
    gqa_attn3<<<dim3(1024), 256, 0, stream>>>(qkv, scratch);  // overwrites xb (dead)
    conv_f2b<<<(int)(WO_E / 8 / 256), 256, 0, stream>>>(W_o, wob, (int)(WO_E / 8));
    gemm_bt_p<true>
        <<<dim3(EMB / 128, M / 128), 256, 0, stream>>>(scratch, wob, out, M, EMB, EMB, EMB);
}